// Round 2
// baseline (514.937 us; speedup 1.0000x reference)
//
#include <hip/hip_runtime.h>
#include <hip/hip_bf16.h>

#define N_NODES 50000
#define N_EDGES 800000
#define HID 128

typedef __bf16 bf16x8 __attribute__((ext_vector_type(8)));
typedef float f32x4 __attribute__((ext_vector_type(4)));

// ---------------------------------------------------------------------------
// Repack f32 weight matrices into bf16 MFMA-B-fragment-major layout:
// out[m][((kstep*8 + ntile)*64 + lane)*8 + j] = W_m[kstep*32 + (lane>>4)*8 + j][ntile*16 + (lane&15)]
// m=0: W_in, m=1: W1[:128] (dst half), m=2: W1[128:] (src half), m=3: W2
// ---------------------------------------------------------------------------
__global__ __launch_bounds__(256) void swizzle_w(
    const float* __restrict__ Win, const float* __restrict__ W1,
    const float* __restrict__ W2, __bf16* __restrict__ out)
{
    int id = blockIdx.x * 256 + threadIdx.x;   // 0..65535
    int m     = id >> 14;
    int rem   = id & 16383;
    int j     = rem & 7;
    int lane  = (rem >> 3) & 63;
    int ntile = (rem >> 9) & 7;
    int kstep = rem >> 12;
    int k = kstep * 32 + (lane >> 4) * 8 + j;
    int n = ntile * 16 + (lane & 15);
    float v;
    if (m == 0)      v = Win[k * HID + n];
    else if (m == 1) v = W1[k * HID + n];
    else if (m == 2) v = W1[(k + HID) * HID + n];
    else             v = W2[k * HID + n];
    out[id] = (__bf16)v;
}

// ---------------------------------------------------------------------------
// h = relu(x @ W_in + b_in), x f32 -> staged bf16, h stored bf16.
// Block: 256 thr = 4 waves; 128 rows/block, wave handles 32 rows (2 m-tiles).
// ---------------------------------------------------------------------------
__global__ __launch_bounds__(256) void proj_kernel(
    const float* __restrict__ x, const __bf16* __restrict__ Wsw,
    const float* __restrict__ b_in, __bf16* __restrict__ h)
{
    __shared__ __bf16 At[128][136];   // +8 pad: 16B-aligned rows, breaks bank aliasing
    int tid = threadIdx.x;
    int wave = tid >> 6, lane = tid & 63;
    int m0 = blockIdx.x * 128;

    // stage x tile: 128 rows x 128 f32; 1 float4 per thread per pass, cvt to bf16
    for (int i = tid; i < 128 * 32; i += 256) {
        int r = i >> 5, c = i & 31;
        int row = m0 + r;
        float4 v = make_float4(0.f, 0.f, 0.f, 0.f);
        if (row < N_NODES) v = *(const float4*)(x + (long)row * HID + c * 4);
        __bf16* dst = &At[r][c * 4];
        dst[0] = (__bf16)v.x; dst[1] = (__bf16)v.y;
        dst[2] = (__bf16)v.z; dst[3] = (__bf16)v.w;
    }
    __syncthreads();

    f32x4 acc[2][8] = {};
    int r_lane = lane & 15;
    int quad = lane >> 4;
#pragma unroll
    for (int ks = 0; ks < 4; ++ks) {
        int kb = ks * 32 + quad * 8;
        bf16x8 a0 = *(const bf16x8*)(&At[wave * 32 + r_lane][kb]);
        bf16x8 a1 = *(const bf16x8*)(&At[wave * 32 + 16 + r_lane][kb]);
#pragma unroll
        for (int n = 0; n < 8; ++n) {
            bf16x8 b = *(const bf16x8*)(Wsw + ((ks * 8 + n) * 64 + lane) * 8);
            acc[0][n] = __builtin_amdgcn_mfma_f32_16x16x32_bf16(a0, b, acc[0][n], 0, 0, 0);
            acc[1][n] = __builtin_amdgcn_mfma_f32_16x16x32_bf16(a1, b, acc[1][n], 0, 0, 0);
        }
    }
#pragma unroll
    for (int n = 0; n < 8; ++n) {
        int col = n * 16 + r_lane;
        float bias = b_in[col];
#pragma unroll
        for (int mt = 0; mt < 2; ++mt) {
            int rbase = m0 + wave * 32 + mt * 16 + quad * 4;
#pragma unroll
            for (int r = 0; r < 4; ++r) {
                int row = rbase + r;
                if (row < N_NODES) {
                    float v = acc[mt][n][r] + bias;
                    h[(long)row * HID + col] = (__bf16)(v > 0.f ? v : 0.f);
                }
            }
        }
    }
}

// ---------------------------------------------------------------------------
// Edge MLP + scatter: per 128-edge tile
//   t = relu(h[dst] @ W1a + h[src] @ W1b + b1)   (to LDS, bf16)
//   m = t @ W2 + b2
//   atomicAdd into h2[dst]  (f32)
// ---------------------------------------------------------------------------
__global__ __launch_bounds__(256) void edge_kernel(
    const __bf16* __restrict__ h, const int* __restrict__ edge_index,
    const __bf16* __restrict__ Wsw, const float* __restrict__ b1,
    const float* __restrict__ b2, float* __restrict__ h2)
{
    __shared__ int ssrc[128];
    __shared__ int sdst[128];
    __shared__ __bf16 T[128][136];

    int tid = threadIdx.x;
    int wave = tid >> 6, lane = tid & 63;
    long e0 = (long)blockIdx.x * 128;

    if (tid < 128)       ssrc[tid] = edge_index[e0 + tid];
    else                 sdst[tid - 128] = edge_index[(long)N_EDGES + e0 + (tid - 128)];
    __syncthreads();

    const __bf16* W1a = Wsw + 16384;   // dst half (W1[:128])
    const __bf16* W1b = Wsw + 32768;   // src half (W1[128:])
    const __bf16* W2  = Wsw + 49152;

    int r_lane = lane & 15;
    int quad = lane >> 4;

    // ---- stage 1 ----
    f32x4 acc[2][8] = {};
#pragma unroll
    for (int ks = 0; ks < 4; ++ks) {
        int kb = ks * 32 + quad * 8;
        bf16x8 ad[2], as_[2];
#pragma unroll
        for (int mt = 0; mt < 2; ++mt) {
            int er = wave * 32 + mt * 16 + r_lane;
            ad[mt]  = *(const bf16x8*)(h + (long)sdst[er] * HID + kb);
            as_[mt] = *(const bf16x8*)(h + (long)ssrc[er] * HID + kb);
        }
#pragma unroll
        for (int n = 0; n < 8; ++n) {
            bf16x8 b_d = *(const bf16x8*)(W1a + ((ks * 8 + n) * 64 + lane) * 8);
            bf16x8 b_s = *(const bf16x8*)(W1b + ((ks * 8 + n) * 64 + lane) * 8);
#pragma unroll
            for (int mt = 0; mt < 2; ++mt) {
                acc[mt][n] = __builtin_amdgcn_mfma_f32_16x16x32_bf16(ad[mt],  b_d, acc[mt][n], 0, 0, 0);
                acc[mt][n] = __builtin_amdgcn_mfma_f32_16x16x32_bf16(as_[mt], b_s, acc[mt][n], 0, 0, 0);
            }
        }
    }
    // epilogue 1: +b1, relu, to LDS (wave-private row slab -> no barrier needed)
#pragma unroll
    for (int n = 0; n < 8; ++n) {
        int col = n * 16 + r_lane;
        float bias = b1[col];
#pragma unroll
        for (int mt = 0; mt < 2; ++mt) {
            int rb = wave * 32 + mt * 16 + quad * 4;
#pragma unroll
            for (int r = 0; r < 4; ++r) {
                float v = acc[mt][n][r] + bias;
                T[rb + r][col] = (__bf16)(v > 0.f ? v : 0.f);
            }
        }
    }

    // ---- stage 2 ----
    f32x4 acc2[2][8] = {};
#pragma unroll
    for (int ks = 0; ks < 4; ++ks) {
        int kb = ks * 32 + quad * 8;
        bf16x8 a0 = *(const bf16x8*)(&T[wave * 32 + r_lane][kb]);
        bf16x8 a1 = *(const bf16x8*)(&T[wave * 32 + 16 + r_lane][kb]);
#pragma unroll
        for (int n = 0; n < 8; ++n) {
            bf16x8 b = *(const bf16x8*)(W2 + ((ks * 8 + n) * 64 + lane) * 8);
            acc2[0][n] = __builtin_amdgcn_mfma_f32_16x16x32_bf16(a0, b, acc2[0][n], 0, 0, 0);
            acc2[1][n] = __builtin_amdgcn_mfma_f32_16x16x32_bf16(a1, b, acc2[1][n], 0, 0, 0);
        }
    }
    // epilogue 2: +b2, scatter-add
#pragma unroll
    for (int n = 0; n < 8; ++n) {
        int col = n * 16 + r_lane;
        float bias = b2[col];
#pragma unroll
        for (int mt = 0; mt < 2; ++mt) {
            int rb = wave * 32 + mt * 16 + quad * 4;
#pragma unroll
            for (int r = 0; r < 4; ++r) {
                int d = sdst[rb + r];
                atomicAdd(&h2[(long)d * HID + col], acc2[mt][n][r] + bias);
            }
        }
    }
}

// ---------------------------------------------------------------------------
// out = relu(h2) @ Wc + bc   (N=2, f32 out). 16 lanes per node, shfl reduce.
// ---------------------------------------------------------------------------
__global__ __launch_bounds__(256) void cls_kernel(
    const float* __restrict__ h2, const float* __restrict__ Wc,
    const float* __restrict__ bc, float* __restrict__ out)
{
    int tid = threadIdx.x;
    int wave = tid >> 6, lane = tid & 63;
    int g = lane >> 4, li = lane & 15;
    int node = blockIdx.x * 16 + wave * 4 + g;
    if (node >= N_NODES) return;

    const float* row = h2 + (long)node * HID + li * 8;
    float a0 = 0.f, a1 = 0.f;
#pragma unroll
    for (int j = 0; j < 8; ++j) {
        float v = row[j];
        v = v > 0.f ? v : 0.f;
        int k = li * 8 + j;
        a0 += v * Wc[k * 2 + 0];
        a1 += v * Wc[k * 2 + 1];
    }
#pragma unroll
    for (int off = 1; off < 16; off <<= 1) {
        a0 += __shfl_xor(a0, off);
        a1 += __shfl_xor(a1, off);
    }
    if (li == 0) {
        out[(long)node * 2 + 0] = a0 + bc[0];
        out[(long)node * 2 + 1] = a1 + bc[1];
    }
}

extern "C" void kernel_launch(void* const* d_in, const int* in_sizes, int n_in,
                              void* d_out, int out_size, void* d_ws, size_t ws_size,
                              hipStream_t stream) {
    const float* x    = (const float*)d_in[0];
    const int* eidx   = (const int*)d_in[1];
    const float* W_in = (const float*)d_in[2];
    const float* b_in = (const float*)d_in[3];
    const float* W1   = (const float*)d_in[4];
    const float* b1   = (const float*)d_in[5];
    const float* W2   = (const float*)d_in[6];
    const float* b2   = (const float*)d_in[7];
    const float* Wc   = (const float*)d_in[8];
    const float* bc   = (const float*)d_in[9];
    float* out = (float*)d_out;

    char* ws = (char*)d_ws;
    __bf16* h    = (__bf16*)ws;                               // 50000*128*2  = 12,800,000 B
    float*  h2   = (float*)(ws + 12800000);                   // 50000*128*4  = 25,600,000 B
    __bf16* Wsw  = (__bf16*)(ws + 12800000 + 25600000);       // 4*16384*2    =    131,072 B

    hipMemsetAsync(h2, 0, (size_t)N_NODES * HID * sizeof(float), stream);
    swizzle_w<<<256, 256, 0, stream>>>(W_in, W1, W2, Wsw);
    proj_kernel<<<(N_NODES + 127) / 128, 256, 0, stream>>>(x, Wsw, b_in, h);
    edge_kernel<<<N_EDGES / 128, 256, 0, stream>>>(h, eidx, Wsw, b1, b2, h2);
    cls_kernel<<<(N_NODES + 15) / 16, 256, 0, stream>>>(h2, Wc, bc, out);
}

// Round 3
// 460.205 us; speedup vs baseline: 1.1189x; 1.1189x over previous
//
#include <hip/hip_runtime.h>
#include <hip/hip_bf16.h>

#define N_NODES 50000
#define N_EDGES 800000
#define HID 128
#define SCAN_B 196   // ceil(50000/256)

typedef __bf16 bf16x8 __attribute__((ext_vector_type(8)));
typedef float f32x4 __attribute__((ext_vector_type(4)));

// ---------------------------------------------------------------------------
// Repack f32 weight matrices into bf16 MFMA-B-fragment-major layout:
// out[m][((kstep*8 + ntile)*64 + lane)*8 + j] = W_m[kstep*32 + (lane>>4)*8 + j][ntile*16 + (lane&15)]
// m=0: W_in, m=1: W1[:128] (dst half), m=2: W1[128:] (src half), m=3: W2
// ---------------------------------------------------------------------------
__global__ __launch_bounds__(256) void swizzle_w(
    const float* __restrict__ Win, const float* __restrict__ W1,
    const float* __restrict__ W2, __bf16* __restrict__ out)
{
    int id = blockIdx.x * 256 + threadIdx.x;   // 0..65535
    int m     = id >> 14;
    int rem   = id & 16383;
    int j     = rem & 7;
    int lane  = (rem >> 3) & 63;
    int ntile = (rem >> 9) & 7;
    int kstep = rem >> 12;
    int k = kstep * 32 + (lane >> 4) * 8 + j;
    int n = ntile * 16 + (lane & 15);
    float v;
    if (m == 0)      v = Win[k * HID + n];
    else if (m == 1) v = W1[k * HID + n];
    else if (m == 2) v = W1[(k + HID) * HID + n];
    else             v = W2[k * HID + n];
    out[id] = (__bf16)v;
}

// ---------------------------------------------------------------------------
// h = relu(x @ W_in + b_in), x f32 staged to bf16 LDS, h stored bf16.
// ---------------------------------------------------------------------------
__global__ __launch_bounds__(256) void proj_kernel(
    const float* __restrict__ x, const __bf16* __restrict__ Wsw,
    const float* __restrict__ b_in, __bf16* __restrict__ h)
{
    __shared__ __bf16 At[128][136];
    int tid = threadIdx.x;
    int wave = tid >> 6, lane = tid & 63;
    int m0 = blockIdx.x * 128;

    for (int i = tid; i < 128 * 32; i += 256) {
        int r = i >> 5, c = i & 31;
        int row = m0 + r;
        float4 v = make_float4(0.f, 0.f, 0.f, 0.f);
        if (row < N_NODES) v = *(const float4*)(x + (long)row * HID + c * 4);
        __bf16* dst = &At[r][c * 4];
        dst[0] = (__bf16)v.x; dst[1] = (__bf16)v.y;
        dst[2] = (__bf16)v.z; dst[3] = (__bf16)v.w;
    }
    __syncthreads();

    f32x4 acc[2][8] = {};
    int r_lane = lane & 15, quad = lane >> 4;
#pragma unroll
    for (int ks = 0; ks < 4; ++ks) {
        int kb = ks * 32 + quad * 8;
        bf16x8 a0 = *(const bf16x8*)(&At[wave * 32 + r_lane][kb]);
        bf16x8 a1 = *(const bf16x8*)(&At[wave * 32 + 16 + r_lane][kb]);
#pragma unroll
        for (int n = 0; n < 8; ++n) {
            bf16x8 b = *(const bf16x8*)(Wsw + ((ks * 8 + n) * 64 + lane) * 8);
            acc[0][n] = __builtin_amdgcn_mfma_f32_16x16x32_bf16(a0, b, acc[0][n], 0, 0, 0);
            acc[1][n] = __builtin_amdgcn_mfma_f32_16x16x32_bf16(a1, b, acc[1][n], 0, 0, 0);
        }
    }
#pragma unroll
    for (int n = 0; n < 8; ++n) {
        int col = n * 16 + r_lane;
        float bias = b_in[col];
#pragma unroll
        for (int mt = 0; mt < 2; ++mt) {
            int rbase = m0 + wave * 32 + mt * 16 + quad * 4;
#pragma unroll
            for (int r = 0; r < 4; ++r) {
                int row = rbase + r;
                if (row < N_NODES) {
                    float v = acc[mt][n][r] + bias;
                    h[(long)row * HID + col] = (__bf16)(v > 0.f ? v : 0.f);
                }
            }
        }
    }
}

// ---------------------------------------------------------------------------
// Pd = h @ W1a + b1  (f32, no relu). Per-node precompute of the dst half.
// ---------------------------------------------------------------------------
__global__ __launch_bounds__(256) void pd_kernel(
    const __bf16* __restrict__ h, const __bf16* __restrict__ Wsw,
    const float* __restrict__ b1, float* __restrict__ Pd)
{
    __shared__ __bf16 At[128][136];
    int tid = threadIdx.x;
    int wave = tid >> 6, lane = tid & 63;
    int m0 = blockIdx.x * 128;

    for (int i = tid; i < 128 * 16; i += 256) {
        int r = i >> 4, c = i & 15;
        int row = m0 + r;
        uint4 v = make_uint4(0u, 0u, 0u, 0u);
        if (row < N_NODES) v = *(const uint4*)(h + (long)row * HID + c * 8);
        *(uint4*)(&At[r][c * 8]) = v;
    }
    __syncthreads();

    const __bf16* W1a = Wsw + 16384;
    f32x4 acc[2][8] = {};
    int r_lane = lane & 15, quad = lane >> 4;
#pragma unroll
    for (int ks = 0; ks < 4; ++ks) {
        int kb = ks * 32 + quad * 8;
        bf16x8 a0 = *(const bf16x8*)(&At[wave * 32 + r_lane][kb]);
        bf16x8 a1 = *(const bf16x8*)(&At[wave * 32 + 16 + r_lane][kb]);
#pragma unroll
        for (int n = 0; n < 8; ++n) {
            bf16x8 b = *(const bf16x8*)(W1a + ((ks * 8 + n) * 64 + lane) * 8);
            acc[0][n] = __builtin_amdgcn_mfma_f32_16x16x32_bf16(a0, b, acc[0][n], 0, 0, 0);
            acc[1][n] = __builtin_amdgcn_mfma_f32_16x16x32_bf16(a1, b, acc[1][n], 0, 0, 0);
        }
    }
#pragma unroll
    for (int n = 0; n < 8; ++n) {
        int col = n * 16 + r_lane;
        float bias = b1[col];
#pragma unroll
        for (int mt = 0; mt < 2; ++mt) {
            int rbase = m0 + wave * 32 + mt * 16 + quad * 4;
#pragma unroll
            for (int r = 0; r < 4; ++r) {
                int row = rbase + r;
                if (row < N_NODES) Pd[(long)row * HID + col] = acc[mt][n][r] + bias;
            }
        }
    }
}

// ---------------------------------------------------------------------------
// Sort pipeline: histogram -> exclusive scan -> stable-ish permutation
// ---------------------------------------------------------------------------
__global__ __launch_bounds__(256) void hist_kernel(
    const int* __restrict__ eidx, int* __restrict__ hist)
{
    int e = blockIdx.x * 256 + threadIdx.x;
    if (e < N_EDGES) atomicAdd(&hist[eidx[N_EDGES + e]], 1);
}

__global__ __launch_bounds__(256) void scan_a(
    const int* __restrict__ hist, int* __restrict__ offs, int* __restrict__ bsum)
{
    __shared__ int s[256];
    int t = threadIdx.x;
    int i = blockIdx.x * 256 + t;
    int v = (i < N_NODES) ? hist[i] : 0;
    s[t] = v;
    __syncthreads();
    for (int d = 1; d < 256; d <<= 1) {
        int tv = (t >= d) ? s[t - d] : 0;
        __syncthreads();
        s[t] += tv;
        __syncthreads();
    }
    if (i < N_NODES) offs[i] = s[t] - v;       // block-local exclusive
    if (t == 255) bsum[blockIdx.x] = s[255];   // block total
}

__global__ __launch_bounds__(64) void scan_b(int* __restrict__ bsum)
{
    if (threadIdx.x == 0) {
        int run = 0;
        for (int b = 0; b < SCAN_B; ++b) { int v = bsum[b]; bsum[b] = run; run += v; }
    }
}

__global__ __launch_bounds__(256) void scan_c(
    int* __restrict__ offs, const int* __restrict__ bsum, int* __restrict__ cursor)
{
    int i = blockIdx.x * 256 + threadIdx.x;
    if (i < N_NODES) {
        int o = offs[i] + bsum[blockIdx.x];
        offs[i] = o;
        cursor[i] = o;
    }
}

__global__ __launch_bounds__(256) void permute_kernel(
    const int* __restrict__ eidx, int* __restrict__ cursor,
    int* __restrict__ ssrc_g, int* __restrict__ sdst_g)
{
    int e = blockIdx.x * 256 + threadIdx.x;
    if (e < N_EDGES) {
        int d = eidx[N_EDGES + e];
        int pos = atomicAdd(&cursor[d], 1);
        sdst_g[pos] = d;
        ssrc_g[pos] = eidx[e];
    }
}

// ---------------------------------------------------------------------------
// Edge stage-1 on dst-sorted edges + in-tile segmented reduction into Tagg.
//   t_e = relu( Pd[dst_e] + h[src_e]@W1b )          (use_pd==1)
//   t_e = relu( h[dst_e]@W1a + h[src_e]@W1b + b1 )  (use_pd==0)
//   Tagg[d] += sum of t_e over the segment (f32 atomics, ~9 per 128-edge tile)
// ---------------------------------------------------------------------------
__global__ __launch_bounds__(256) void edge1_kernel(
    const __bf16* __restrict__ h, const int* __restrict__ ssrc_g,
    const int* __restrict__ sdst_g, const __bf16* __restrict__ Wsw,
    const float* __restrict__ b1, const float* __restrict__ Pd,
    float* __restrict__ Tagg, int use_pd)
{
    __shared__ int ssrc[128];
    __shared__ int sdst[128];
    __shared__ __bf16 T[128][136];

    int tid = threadIdx.x;
    int wave = tid >> 6, lane = tid & 63;
    int e0 = blockIdx.x * 128;

    if (tid < 128)       ssrc[tid] = ssrc_g[e0 + tid];
    else                 sdst[tid - 128] = sdst_g[e0 + (tid - 128)];
    __syncthreads();

    const __bf16* W1a = Wsw + 16384;
    const __bf16* W1b = Wsw + 32768;
    int r_lane = lane & 15, quad = lane >> 4;

    f32x4 acc[2][8] = {};
    if (use_pd) {
#pragma unroll
        for (int ks = 0; ks < 4; ++ks) {
            int kb = ks * 32 + quad * 8;
            bf16x8 as_[2];
#pragma unroll
            for (int mt = 0; mt < 2; ++mt) {
                int er = wave * 32 + mt * 16 + r_lane;
                as_[mt] = *(const bf16x8*)(h + (long)ssrc[er] * HID + kb);
            }
#pragma unroll
            for (int n = 0; n < 8; ++n) {
                bf16x8 b_s = *(const bf16x8*)(W1b + ((ks * 8 + n) * 64 + lane) * 8);
#pragma unroll
                for (int mt = 0; mt < 2; ++mt)
                    acc[mt][n] = __builtin_amdgcn_mfma_f32_16x16x32_bf16(as_[mt], b_s, acc[mt][n], 0, 0, 0);
            }
        }
    } else {
#pragma unroll
        for (int ks = 0; ks < 4; ++ks) {
            int kb = ks * 32 + quad * 8;
            bf16x8 ad[2], as_[2];
#pragma unroll
            for (int mt = 0; mt < 2; ++mt) {
                int er = wave * 32 + mt * 16 + r_lane;
                ad[mt]  = *(const bf16x8*)(h + (long)sdst[er] * HID + kb);
                as_[mt] = *(const bf16x8*)(h + (long)ssrc[er] * HID + kb);
            }
#pragma unroll
            for (int n = 0; n < 8; ++n) {
                bf16x8 b_d = *(const bf16x8*)(W1a + ((ks * 8 + n) * 64 + lane) * 8);
                bf16x8 b_s = *(const bf16x8*)(W1b + ((ks * 8 + n) * 64 + lane) * 8);
#pragma unroll
                for (int mt = 0; mt < 2; ++mt) {
                    acc[mt][n] = __builtin_amdgcn_mfma_f32_16x16x32_bf16(ad[mt],  b_d, acc[mt][n], 0, 0, 0);
                    acc[mt][n] = __builtin_amdgcn_mfma_f32_16x16x32_bf16(as_[mt], b_s, acc[mt][n], 0, 0, 0);
                }
            }
        }
    }

    // epilogue: t = relu(acc [+ Pd[dst]] [+ b1]) -> LDS bf16 (wave-private rows)
#pragma unroll
    for (int n = 0; n < 8; ++n) {
        int col = n * 16 + r_lane;
        float bias = use_pd ? 0.f : b1[col];
#pragma unroll
        for (int mt = 0; mt < 2; ++mt) {
            int rb = wave * 32 + mt * 16 + quad * 4;
#pragma unroll
            for (int r = 0; r < 4; ++r) {
                int row = rb + r;
                float v = acc[mt][n][r] + bias;
                if (use_pd) v += Pd[(long)sdst[row] * HID + col];
                T[row][col] = (__bf16)(v > 0.f ? v : 0.f);
            }
        }
    }
    __syncthreads();

    // segmented reduction: 2 threads per column, 64 rows each
    int half = tid >> 7, col = tid & 127;
    int r0 = half * 64;
    float run = 0.f;
    int cur = sdst[r0];
    for (int r = r0; r < r0 + 64; ++r) {
        int d = sdst[r];
        if (d != cur) {
            atomicAdd(&Tagg[(long)cur * HID + col], run);
            run = 0.f;
            cur = d;
        }
        run += (float)T[r][col];
    }
    atomicAdd(&Tagg[(long)cur * HID + col], run);
}

// ---------------------------------------------------------------------------
// Node finish: h2 = relu(Tagg @ W2 + deg*b2); out = h2 @ Wc + bc (fused).
// ---------------------------------------------------------------------------
__global__ __launch_bounds__(256) void node_kernel(
    const float* __restrict__ Tagg, const __bf16* __restrict__ Wsw,
    const int* __restrict__ hist, const float* __restrict__ b2,
    const float* __restrict__ Wc, const float* __restrict__ bc,
    float* __restrict__ out)
{
    __shared__ __bf16 At[128][136];
    int tid = threadIdx.x;
    int wave = tid >> 6, lane = tid & 63;
    int m0 = blockIdx.x * 128;

    for (int i = tid; i < 128 * 32; i += 256) {
        int r = i >> 5, c = i & 31;
        int row = m0 + r;
        float4 v = make_float4(0.f, 0.f, 0.f, 0.f);
        if (row < N_NODES) v = *(const float4*)(Tagg + (long)row * HID + c * 4);
        __bf16* dst = &At[r][c * 4];
        dst[0] = (__bf16)v.x; dst[1] = (__bf16)v.y;
        dst[2] = (__bf16)v.z; dst[3] = (__bf16)v.w;
    }
    __syncthreads();

    const __bf16* W2f = Wsw + 49152;
    f32x4 acc[2][8] = {};
    int r_lane = lane & 15, quad = lane >> 4;
#pragma unroll
    for (int ks = 0; ks < 4; ++ks) {
        int kb = ks * 32 + quad * 8;
        bf16x8 a0 = *(const bf16x8*)(&At[wave * 32 + r_lane][kb]);
        bf16x8 a1 = *(const bf16x8*)(&At[wave * 32 + 16 + r_lane][kb]);
#pragma unroll
        for (int n = 0; n < 8; ++n) {
            bf16x8 b = *(const bf16x8*)(W2f + ((ks * 8 + n) * 64 + lane) * 8);
            acc[0][n] = __builtin_amdgcn_mfma_f32_16x16x32_bf16(a0, b, acc[0][n], 0, 0, 0);
            acc[1][n] = __builtin_amdgcn_mfma_f32_16x16x32_bf16(a1, b, acc[1][n], 0, 0, 0);
        }
    }

#pragma unroll
    for (int mt = 0; mt < 2; ++mt) {
#pragma unroll
        for (int r = 0; r < 4; ++r) {
            int row = m0 + wave * 32 + mt * 16 + quad * 4 + r;
            float deg = (row < N_NODES) ? (float)hist[row] : 0.f;
            float s0 = 0.f, s1 = 0.f;
#pragma unroll
            for (int n = 0; n < 8; ++n) {
                int col = n * 16 + r_lane;
                float v = acc[mt][n][r] + deg * b2[col];
                v = v > 0.f ? v : 0.f;
                s0 += v * Wc[col * 2 + 0];
                s1 += v * Wc[col * 2 + 1];
            }
#pragma unroll
            for (int off = 1; off < 16; off <<= 1) {
                s0 += __shfl_xor(s0, off);
                s1 += __shfl_xor(s1, off);
            }
            if (r_lane == 0 && row < N_NODES) {
                out[(long)row * 2 + 0] = s0 + bc[0];
                out[(long)row * 2 + 1] = s1 + bc[1];
            }
        }
    }
}

extern "C" void kernel_launch(void* const* d_in, const int* in_sizes, int n_in,
                              void* d_out, int out_size, void* d_ws, size_t ws_size,
                              hipStream_t stream) {
    const float* x    = (const float*)d_in[0];
    const int* eidx   = (const int*)d_in[1];
    const float* W_in = (const float*)d_in[2];
    const float* b_in = (const float*)d_in[3];
    const float* W1   = (const float*)d_in[4];
    const float* b1   = (const float*)d_in[5];
    const float* W2   = (const float*)d_in[6];
    const float* b2   = (const float*)d_in[7];
    const float* Wc   = (const float*)d_in[8];
    const float* bc   = (const float*)d_in[9];
    float* out = (float*)d_out;

    char* ws = (char*)d_ws;
    __bf16* h     = (__bf16*)(ws + 0);             // 12,800,000
    float*  Tagg  = (float*)(ws + 12800000);       // 25,600,000
    int* sorted_src = (int*)(ws + 38400000);       //  3,200,000
    int* sorted_dst = (int*)(ws + 41600000);       //  3,200,000
    int* hist     = (int*)(ws + 44800000);         //    200,000
    int* offs     = (int*)(ws + 45000000);         //    200,000
    int* cursor   = (int*)(ws + 45200000);         //    200,000
    int* bsum     = (int*)(ws + 45400000);         //      1,024
    __bf16* Wsw   = (__bf16*)(ws + 45401024);      //    131,072
    const size_t base_total = 45532096;
    int use_pd = (ws_size >= base_total + (size_t)N_NODES * HID * 4) ? 1 : 0;
    float* Pd = use_pd ? (float*)(ws + base_total) : (float*)Tagg /*unused*/;

    hipMemsetAsync(hist, 0, (size_t)N_NODES * sizeof(int), stream);
    hipMemsetAsync(Tagg, 0, (size_t)N_NODES * HID * sizeof(float), stream);

    swizzle_w<<<256, 256, 0, stream>>>(W_in, W1, W2, Wsw);
    proj_kernel<<<(N_NODES + 127) / 128, 256, 0, stream>>>(x, Wsw, b_in, h);

    hist_kernel<<<(N_EDGES + 255) / 256, 256, 0, stream>>>(eidx, hist);
    scan_a<<<SCAN_B, 256, 0, stream>>>(hist, offs, bsum);
    scan_b<<<1, 64, 0, stream>>>(bsum);
    scan_c<<<SCAN_B, 256, 0, stream>>>(offs, bsum, cursor);
    permute_kernel<<<(N_EDGES + 255) / 256, 256, 0, stream>>>(eidx, cursor, sorted_src, sorted_dst);

    if (use_pd)
        pd_kernel<<<(N_NODES + 127) / 128, 256, 0, stream>>>(h, Wsw, b1, Pd);

    edge1_kernel<<<N_EDGES / 128, 256, 0, stream>>>(h, sorted_src, sorted_dst, Wsw,
                                                    b1, Pd, Tagg, use_pd);
    node_kernel<<<(N_NODES + 127) / 128, 256, 0, stream>>>(Tagg, Wsw, hist, b2, Wc, bc, out);
}

// Round 4
// 350.850 us; speedup vs baseline: 1.4677x; 1.3117x over previous
//
#include <hip/hip_runtime.h>
#include <hip/hip_bf16.h>

#define N_NODES 50000
#define N_EDGES 800000
#define HID 128
#define SCAN_B 196   // ceil(50000/256)

typedef __bf16 bf16x8 __attribute__((ext_vector_type(8)));
typedef __bf16 bf16x4 __attribute__((ext_vector_type(4)));
typedef float f32x4 __attribute__((ext_vector_type(4)));

// ---------------------------------------------------------------------------
// prep: blocks [0,256) repack weights into MFMA-B-fragment-major bf16;
//       blocks [256,3381) histogram edge dst.
// Wsw[m][((kstep*8+ntile)*64+lane)*8+j] = W_m[kstep*32+(lane>>4)*8+j][ntile*16+(lane&15)]
// m=0: W_in, m=1: W1[:128] (dst half), m=2: W1[128:] (src half), m=3: W2
// ---------------------------------------------------------------------------
__global__ __launch_bounds__(256) void prep_kernel(
    const float* __restrict__ Win, const float* __restrict__ W1,
    const float* __restrict__ W2, __bf16* __restrict__ Wsw,
    const int* __restrict__ eidx, int* __restrict__ hist)
{
    int b = blockIdx.x;
    int tid = threadIdx.x;
    if (b < 256) {
        int id = b * 256 + tid;   // 0..65535
        int m     = id >> 14;
        int rem   = id & 16383;
        int j     = rem & 7;
        int lane  = (rem >> 3) & 63;
        int ntile = (rem >> 9) & 7;
        int kstep = rem >> 12;
        int k = kstep * 32 + (lane >> 4) * 8 + j;
        int n = ntile * 16 + (lane & 15);
        float v;
        if (m == 0)      v = Win[k * HID + n];
        else if (m == 1) v = W1[k * HID + n];
        else if (m == 2) v = W1[(k + HID) * HID + n];
        else             v = W2[k * HID + n];
        Wsw[id] = (__bf16)v;
    } else {
        int e = (b - 256) * 256 + tid;
        if (e < N_EDGES) atomicAdd(&hist[eidx[N_EDGES + e]], 1);
    }
}

// ---------------------------------------------------------------------------
// h = relu(x @ W_in + b_in), x f32 staged to bf16 LDS, h stored bf16.
// ---------------------------------------------------------------------------
__global__ __launch_bounds__(256) void proj_kernel(
    const float* __restrict__ x, const __bf16* __restrict__ Wsw,
    const float* __restrict__ b_in, __bf16* __restrict__ h)
{
    __shared__ __bf16 At[128][136];
    int tid = threadIdx.x;
    int wave = tid >> 6, lane = tid & 63;
    int m0 = blockIdx.x * 128;

    for (int i = tid; i < 128 * 32; i += 256) {
        int r = i >> 5, c = i & 31;
        int row = m0 + r;
        float4 v = make_float4(0.f, 0.f, 0.f, 0.f);
        if (row < N_NODES) v = *(const float4*)(x + (long)row * HID + c * 4);
        __bf16* dst = &At[r][c * 4];
        dst[0] = (__bf16)v.x; dst[1] = (__bf16)v.y;
        dst[2] = (__bf16)v.z; dst[3] = (__bf16)v.w;
    }
    __syncthreads();

    f32x4 acc[2][8] = {};
    int r_lane = lane & 15, quad = lane >> 4;
#pragma unroll
    for (int ks = 0; ks < 4; ++ks) {
        int kb = ks * 32 + quad * 8;
        bf16x8 a0 = *(const bf16x8*)(&At[wave * 32 + r_lane][kb]);
        bf16x8 a1 = *(const bf16x8*)(&At[wave * 32 + 16 + r_lane][kb]);
#pragma unroll
        for (int n = 0; n < 8; ++n) {
            bf16x8 b = *(const bf16x8*)(Wsw + ((ks * 8 + n) * 64 + lane) * 8);
            acc[0][n] = __builtin_amdgcn_mfma_f32_16x16x32_bf16(a0, b, acc[0][n], 0, 0, 0);
            acc[1][n] = __builtin_amdgcn_mfma_f32_16x16x32_bf16(a1, b, acc[1][n], 0, 0, 0);
        }
    }
#pragma unroll
    for (int n = 0; n < 8; ++n) {
        int col = n * 16 + r_lane;
        float bias = b_in[col];
#pragma unroll
        for (int mt = 0; mt < 2; ++mt) {
            int rbase = m0 + wave * 32 + mt * 16 + quad * 4;
#pragma unroll
            for (int r = 0; r < 4; ++r) {
                int row = rbase + r;
                if (row < N_NODES) {
                    float v = acc[mt][n][r] + bias;
                    h[(long)row * HID + col] = (__bf16)(v > 0.f ? v : 0.f);
                }
            }
        }
    }
}

// ---------------------------------------------------------------------------
// scan_a: per-block exclusive scan of hist -> loc, block totals -> bsum
// ---------------------------------------------------------------------------
__global__ __launch_bounds__(256) void scan_a(
    const int* __restrict__ hist, int* __restrict__ loc, int* __restrict__ bsum)
{
    __shared__ int s[256];
    int t = threadIdx.x;
    int i = blockIdx.x * 256 + t;
    int v = (i < N_NODES) ? hist[i] : 0;
    s[t] = v;
    __syncthreads();
    for (int d = 1; d < 256; d <<= 1) {
        int tv = (t >= d) ? s[t - d] : 0;
        __syncthreads();
        s[t] += tv;
        __syncthreads();
    }
    if (i < N_NODES) loc[i] = s[t] - v;
    if (t == 255) bsum[blockIdx.x] = s[255];
}

// scan_c: add inter-block prefix (computed inline) -> cursor
__global__ __launch_bounds__(256) void scan_c(
    const int* __restrict__ loc, const int* __restrict__ bsum, int* __restrict__ cursor)
{
    __shared__ int pre;
    if (threadIdx.x == 0) {
        int s = 0;
        for (int b = 0; b < (int)blockIdx.x; ++b) s += bsum[b];
        pre = s;
    }
    __syncthreads();
    int i = blockIdx.x * 256 + threadIdx.x;
    if (i < N_NODES) cursor[i] = loc[i] + pre;
}

// permute: scatter edges into dst-sorted order as int2 (src,dst)
__global__ __launch_bounds__(256) void permute_kernel(
    const int* __restrict__ eidx, int* __restrict__ cursor, int2* __restrict__ es)
{
    int e = blockIdx.x * 256 + threadIdx.x;
    if (e < N_EDGES) {
        int d = eidx[N_EDGES + e];
        int pos = atomicAdd(&cursor[d], 1);
        es[pos] = make_int2(eidx[e], d);
    }
}

// ---------------------------------------------------------------------------
// Edge stage-1 on dst-sorted edges:
//   t_e = relu( h[dst]@W1a + h[src]@W1b + b1 )  -> Tt (transposed, bf16, LDS)
//   segmented reduce over rows (wave-uniform bitmask control) -> atomics into Tagg
// ---------------------------------------------------------------------------
__global__ __launch_bounds__(256) void edge1_kernel(
    const __bf16* __restrict__ h, const int2* __restrict__ es,
    const __bf16* __restrict__ Wsw, const float* __restrict__ b1,
    float* __restrict__ Tagg)
{
    __shared__ int ssrc[128];
    __shared__ int sdst[128];
    __shared__ unsigned long long masks[2];
    __shared__ __bf16 Tt[128][136];   // [col][row]; stride 136 balances banks

    int tid = threadIdx.x;
    int wave = tid >> 6, lane = tid & 63;
    int e0 = blockIdx.x * 128;

    if (tid < 128) {
        int2 e = es[e0 + tid];
        ssrc[tid] = e.x;
        sdst[tid] = e.y;
    }
    __syncthreads();

    // boundary flags -> two 64-bit masks (bit l of masks[w] = row w*64+l starts new seg)
    if (tid < 128) {
        bool flag = (tid > 0) && (sdst[tid] != sdst[tid - 1]);
        unsigned long long m = __ballot(flag);
        if (lane == 0) masks[wave] = m;
    }

    const __bf16* W1a = Wsw + 16384;
    const __bf16* W1b = Wsw + 32768;
    int r_lane = lane & 15, quad = lane >> 4;

    f32x4 acc[2][8] = {};
#pragma unroll
    for (int ks = 0; ks < 4; ++ks) {
        int kb = ks * 32 + quad * 8;
        bf16x8 ad[2], as_[2];
#pragma unroll
        for (int mt = 0; mt < 2; ++mt) {
            int er = wave * 32 + mt * 16 + r_lane;
            ad[mt]  = *(const bf16x8*)(h + (long)sdst[er] * HID + kb);
            as_[mt] = *(const bf16x8*)(h + (long)ssrc[er] * HID + kb);
        }
#pragma unroll
        for (int n = 0; n < 8; ++n) {
            bf16x8 b_d = *(const bf16x8*)(W1a + ((ks * 8 + n) * 64 + lane) * 8);
            bf16x8 b_s = *(const bf16x8*)(W1b + ((ks * 8 + n) * 64 + lane) * 8);
#pragma unroll
            for (int mt = 0; mt < 2; ++mt) {
                acc[mt][n] = __builtin_amdgcn_mfma_f32_16x16x32_bf16(ad[mt],  b_d, acc[mt][n], 0, 0, 0);
                acc[mt][n] = __builtin_amdgcn_mfma_f32_16x16x32_bf16(as_[mt], b_s, acc[mt][n], 0, 0, 0);
            }
        }
    }

    // epilogue: relu(acc+b1) -> Tt[col][row], packed 4-row b64 stores
#pragma unroll
    for (int n = 0; n < 8; ++n) {
        int col = n * 16 + r_lane;
        float bias = b1[col];
#pragma unroll
        for (int mt = 0; mt < 2; ++mt) {
            int rb = wave * 32 + mt * 16 + quad * 4;
            bf16x4 v4;
#pragma unroll
            for (int r = 0; r < 4; ++r) {
                float v = acc[mt][n][r] + bias;
                v4[r] = (__bf16)(v > 0.f ? v : 0.f);
            }
            *(bf16x4*)(&Tt[col][rb]) = v4;
        }
    }
    __syncthreads();

    // segmented reduction: thread = (half, col); 64 rows via 8 x ds_read_b128
    int half = tid >> 7;
    int col  = tid & 127;
    unsigned long long mask = masks[half];
    int rbase = half * 64;
    float accv = 0.f;
#pragma unroll
    for (int blk = 0; blk < 8; ++blk) {
        bf16x8 v = *(const bf16x8*)(&Tt[col][rbase + blk * 8]);
        uint4 u = __builtin_bit_cast(uint4, v);
        float f[8];
        f[0] = __uint_as_float(u.x << 16); f[1] = __uint_as_float(u.x & 0xffff0000u);
        f[2] = __uint_as_float(u.y << 16); f[3] = __uint_as_float(u.y & 0xffff0000u);
        f[4] = __uint_as_float(u.z << 16); f[5] = __uint_as_float(u.z & 0xffff0000u);
        f[6] = __uint_as_float(u.w << 16); f[7] = __uint_as_float(u.w & 0xffff0000u);
#pragma unroll
        for (int j = 0; j < 8; ++j) {
            int l = blk * 8 + j;
            if (l != 0 && ((mask >> l) & 1ull)) {     // wave-uniform branch
                atomicAdd(&Tagg[(long)sdst[rbase + l - 1] * HID + col], accv);
                accv = 0.f;
            }
            accv += f[j];
        }
    }
    atomicAdd(&Tagg[(long)sdst[rbase + 63] * HID + col], accv);
}

// ---------------------------------------------------------------------------
// Node finish: h2 = relu(Tagg @ W2 + deg*b2); out = h2 @ Wc + bc (fused).
// ---------------------------------------------------------------------------
__global__ __launch_bounds__(256) void node_kernel(
    const float* __restrict__ Tagg, const __bf16* __restrict__ Wsw,
    const int* __restrict__ hist, const float* __restrict__ b2,
    const float* __restrict__ Wc, const float* __restrict__ bc,
    float* __restrict__ out)
{
    __shared__ __bf16 At[128][136];
    int tid = threadIdx.x;
    int wave = tid >> 6, lane = tid & 63;
    int m0 = blockIdx.x * 128;

    for (int i = tid; i < 128 * 32; i += 256) {
        int r = i >> 5, c = i & 31;
        int row = m0 + r;
        float4 v = make_float4(0.f, 0.f, 0.f, 0.f);
        if (row < N_NODES) v = *(const float4*)(Tagg + (long)row * HID + c * 4);
        __bf16* dst = &At[r][c * 4];
        dst[0] = (__bf16)v.x; dst[1] = (__bf16)v.y;
        dst[2] = (__bf16)v.z; dst[3] = (__bf16)v.w;
    }
    __syncthreads();

    const __bf16* W2f = Wsw + 49152;
    f32x4 acc[2][8] = {};
    int r_lane = lane & 15, quad = lane >> 4;
#pragma unroll
    for (int ks = 0; ks < 4; ++ks) {
        int kb = ks * 32 + quad * 8;
        bf16x8 a0 = *(const bf16x8*)(&At[wave * 32 + r_lane][kb]);
        bf16x8 a1 = *(const bf16x8*)(&At[wave * 32 + 16 + r_lane][kb]);
#pragma unroll
        for (int n = 0; n < 8; ++n) {
            bf16x8 b = *(const bf16x8*)(W2f + ((ks * 8 + n) * 64 + lane) * 8);
            acc[0][n] = __builtin_amdgcn_mfma_f32_16x16x32_bf16(a0, b, acc[0][n], 0, 0, 0);
            acc[1][n] = __builtin_amdgcn_mfma_f32_16x16x32_bf16(a1, b, acc[1][n], 0, 0, 0);
        }
    }

#pragma unroll
    for (int mt = 0; mt < 2; ++mt) {
#pragma unroll
        for (int r = 0; r < 4; ++r) {
            int row = m0 + wave * 32 + mt * 16 + quad * 4 + r;
            float deg = (row < N_NODES) ? (float)hist[row] : 0.f;
            float s0 = 0.f, s1 = 0.f;
#pragma unroll
            for (int n = 0; n < 8; ++n) {
                int col = n * 16 + r_lane;
                float v = acc[mt][n][r] + deg * b2[col];
                v = v > 0.f ? v : 0.f;
                s0 += v * Wc[col * 2 + 0];
                s1 += v * Wc[col * 2 + 1];
            }
#pragma unroll
            for (int off = 1; off < 16; off <<= 1) {
                s0 += __shfl_xor(s0, off);
                s1 += __shfl_xor(s1, off);
            }
            if (r_lane == 0 && row < N_NODES) {
                out[(long)row * 2 + 0] = s0 + bc[0];
                out[(long)row * 2 + 1] = s1 + bc[1];
            }
        }
    }
}

extern "C" void kernel_launch(void* const* d_in, const int* in_sizes, int n_in,
                              void* d_out, int out_size, void* d_ws, size_t ws_size,
                              hipStream_t stream) {
    const float* x    = (const float*)d_in[0];
    const int* eidx   = (const int*)d_in[1];
    const float* W_in = (const float*)d_in[2];
    const float* b_in = (const float*)d_in[3];
    const float* W1   = (const float*)d_in[4];
    const float* b1   = (const float*)d_in[5];
    const float* W2   = (const float*)d_in[6];
    const float* b2   = (const float*)d_in[7];
    const float* Wc   = (const float*)d_in[8];
    const float* bc   = (const float*)d_in[9];
    float* out = (float*)d_out;

    char* ws = (char*)d_ws;
    __bf16* h   = (__bf16*)(ws + 0);              // 12,800,000
    float* Tagg = (float*)(ws + 12800000);        // 25,600,000
    int2* es    = (int2*)(ws + 38400000);         //  6,400,000
    int* hist   = (int*)(ws + 44800000);          //    200,000
    int* loc    = (int*)(ws + 45000000);          //    200,000
    int* cursor = (int*)(ws + 45200000);          //    200,000
    int* bsum   = (int*)(ws + 45400000);          //      1,024
    __bf16* Wsw = (__bf16*)(ws + 45401024);       //    131,072

    hipMemsetAsync(hist, 0, (size_t)N_NODES * sizeof(int), stream);
    hipMemsetAsync(Tagg, 0, (size_t)N_NODES * HID * sizeof(float), stream);

    prep_kernel<<<256 + (N_EDGES + 255) / 256, 256, 0, stream>>>(W_in, W1, W2, Wsw, eidx, hist);
    proj_kernel<<<(N_NODES + 127) / 128, 256, 0, stream>>>(x, Wsw, b_in, h);
    scan_a<<<SCAN_B, 256, 0, stream>>>(hist, loc, bsum);
    scan_c<<<SCAN_B, 256, 0, stream>>>(loc, bsum, cursor);
    permute_kernel<<<(N_EDGES + 255) / 256, 256, 0, stream>>>(eidx, cursor, es);
    edge1_kernel<<<N_EDGES / 128, 256, 0, stream>>>(h, es, Wsw, b1, Tagg);
    node_kernel<<<(N_NODES + 127) / 128, 256, 0, stream>>>(Tagg, Wsw, hist, b2, Wc, bc, out);
}